// Round 1
// baseline (408.533 us; speedup 1.0000x reference)
//
#include <hip/hip_runtime.h>
#include <stdint.h>

typedef unsigned int u32;
typedef unsigned short u16;
typedef float  f32x4 __attribute__((ext_vector_type(4)));
typedef u32    u32x4 __attribute__((ext_vector_type(4)));
typedef __bf16 bf16x8 __attribute__((ext_vector_type(8)));

// fp32 -> bf16 RNE
static __device__ __forceinline__ u16 f2bf(float f){
  u32 u = __builtin_bit_cast(u32, f);
  return (u16)((u + 0x7FFFu + ((u >> 16) & 1u)) >> 16);
}

static __device__ __forceinline__ void async16(const void* g, void* l){
  __builtin_amdgcn_global_load_lds((const __attribute__((address_space(1))) u32*)g,
                                   (__attribute__((address_space(3))) u32*)l, 16, 0, 0);
}

static __device__ __forceinline__ float wave_sum(float v){
#pragma unroll
  for (int o = 32; o > 0; o >>= 1) v += __shfl_xor(v, o, 64);
  return v;
}

// ---------------- transpose + fp32->bf16 convert: dst[C][R] = src[R][C] ----------------
__global__ __launch_bounds__(256) void k_tcvt(const float* __restrict__ src, u16* __restrict__ dst,
                                              int R, int C){
  __shared__ u16 lt[64*72];
  const int c0 = blockIdx.x * 64, r0 = blockIdx.y * 64;
  const int tid = threadIdx.x;
  const int rr = tid >> 4, c4 = tid & 15;
#pragma unroll
  for (int p = 0; p < 4; ++p){
    int r = rr + p*16;
    f32x4 f = *(const f32x4*)(src + (size_t)(r0 + r)*C + c0 + c4*4);
#pragma unroll
    for (int e = 0; e < 4; ++e) lt[(c4*4 + e)*72 + r] = f2bf(f[e]);
  }
  __syncthreads();
  const int c = tid >> 2, bg = tid & 3;
  const u32x4* lp = (const u32x4*)(lt + c*72 + bg*16);  // 144B row stride, 16B aligned
  u32x4 w0 = lp[0], w1 = lp[1];
  u16* drow = dst + (size_t)(c0 + c)*R + r0 + bg*16;
  *(u32x4*)drow = w0;
  *(u32x4*)(drow + 8) = w1;
}

// ---------------- forward GEMM: C[m][n] = sum_k A32[m][k]*Bt[n][k], M=32768,N=512,K=512 ----
// A fp32 (d_in), Bt bf16 [512][512]; writes Cn = C (bf16 [32768][512]) and Ct = C^T (bf16 [512][32768])
__global__ __launch_bounds__(256) void k_gemm_fwd(const float* __restrict__ A,
                                                  const u16* __restrict__ Bt,
                                                  u16* __restrict__ Cn,
                                                  u16* __restrict__ Ct){
  __shared__ char smem[49152];
  float* sA = (float*)smem;            // [128 rows][16 granules of 4 fp32], granule-XOR swizzle (2*(r&7))
  u16*   sB = (u16*)(smem + 32768);    // [128 rows][8 granules of 8 bf16], granule-XOR swizzle (r&7)
  const int tid = threadIdx.x;
  const int lane = tid & 63, wid = tid >> 6;
  const int wm = wid >> 1, wn = wid & 1;
  const int l15 = lane & 15, q = lane >> 4;
  const int m0 = blockIdx.y * 128, n0 = blockIdx.x * 128;

  f32x4 acc[4][4];
  const f32x4 vzero = {0.f, 0.f, 0.f, 0.f};
#pragma unroll
  for (int a = 0; a < 4; ++a)
#pragma unroll
    for (int b = 0; b < 4; ++b) acc[a][b] = vzero;

#pragma unroll 1
  for (int kt = 0; kt < 8; ++kt){
    const int k0 = kt*64;
#pragma unroll
    for (int it = 0; it < 8; ++it){        // stage A tile: 128x64 fp32 = 2048 x 16B
      int g = it*256 + tid;
      int r = g >> 4, gp = g & 15;
      int gg = gp ^ (2*(r & 7));
      async16(A + (size_t)(m0 + r)*512 + k0 + gg*4, (char*)sA + (size_t)g*16);
    }
#pragma unroll
    for (int it = 0; it < 4; ++it){        // stage B tile: 128x64 bf16 = 1024 x 16B
      int g = it*256 + tid;
      int r = g >> 3, gp = g & 7;
      int gg = gp ^ (r & 7);
      async16(Bt + (size_t)(n0 + r)*512 + k0 + gg*8, (char*)sB + (size_t)g*16);
    }
    __syncthreads();
#pragma unroll
    for (int kk = 0; kk < 2; ++kk){
      bf16x8 af[4], bfv[4];
#pragma unroll
      for (int mt = 0; mt < 4; ++mt){
        int r = wm*64 + mt*16 + l15;
        int gg = (kk*8 + q*2) ^ (2*(r & 7));
        const f32x4* p = (const f32x4*)(sA + (size_t)(r*16 + gg)*4);
        f32x4 f0 = p[0], f1 = p[1];
        bf16x8 a;
        a[0]=(__bf16)f0[0]; a[1]=(__bf16)f0[1]; a[2]=(__bf16)f0[2]; a[3]=(__bf16)f0[3];
        a[4]=(__bf16)f1[0]; a[5]=(__bf16)f1[1]; a[6]=(__bf16)f1[2]; a[7]=(__bf16)f1[3];
        af[mt] = a;
      }
#pragma unroll
      for (int nt = 0; nt < 4; ++nt){
        int r = wn*64 + nt*16 + l15;
        int gg = (kk*4 + q) ^ (r & 7);
        bfv[nt] = *(const bf16x8*)(sB + (size_t)(r*8 + gg)*8);
      }
#pragma unroll
      for (int mt = 0; mt < 4; ++mt)
#pragma unroll
        for (int nt = 0; nt < 4; ++nt)
          acc[mt][nt] = __builtin_amdgcn_mfma_f32_16x16x32_bf16(af[mt], bfv[nt], acc[mt][nt], 0, 0, 0);
    }
    __syncthreads();
  }

  // epilogue: natural bf16 store + transposed store via LDS round-trip
  u16* lt = (u16*)smem;   // [128 n][136 m] bf16 (pad 8 -> rows 272B, 16B aligned)
#pragma unroll
  for (int mt = 0; mt < 4; ++mt)
#pragma unroll
    for (int nt = 0; nt < 4; ++nt){
      f32x4 v = acc[mt][nt];
      u16 b0 = f2bf(v[0]), b1 = f2bf(v[1]), b2 = f2bf(v[2]), b3 = f2bf(v[3]);
      int n = wn*64 + nt*16 + l15;
      int mb = wm*64 + mt*16 + q*4;
      u16* cn = Cn + (size_t)(m0 + mb)*512 + n0 + n;
      cn[0] = b0; cn[512] = b1; cn[1024] = b2; cn[1536] = b3;
      *(u32*)(lt + n*136 + mb)     = (u32)b0 | ((u32)b1 << 16);
      *(u32*)(lt + n*136 + mb + 2) = (u32)b2 | ((u32)b3 << 16);
    }
  __syncthreads();
#pragma unroll
  for (int p = 0; p < 8; ++p){
    int g = p*256 + tid;
    int n = g >> 4, mg = g & 15;
    u32x4 w = *(const u32x4*)(lt + n*136 + mg*8);
    *(u32x4*)(Ct + (size_t)(n0 + n)*32768 + m0 + mg*8) = w;
  }
}

// ---------------- update GEMM: C[i][j] = sum_b A[i][b]*B[j][b]; M=N=512, K=32768, split-K=16 ----
__global__ __launch_bounds__(256) void k_gemm_upd(const u16* __restrict__ A0, const u16* __restrict__ B0,
                                                  const u16* __restrict__ A1, const u16* __restrict__ B1,
                                                  float* __restrict__ part){
  __shared__ char smem[32768];
  u16* sA = (u16*)smem;
  u16* sB = (u16*)(smem + 16384);
  const int tid = threadIdx.x;
  const int lane = tid & 63, wid = tid >> 6;
  const int wm = wid >> 1, wn = wid & 1;
  const int l15 = lane & 15, q = lane >> 4;
  const int z = blockIdx.z;
  const int mat = z >> 4, sp = z & 15;
  const u16* __restrict__ A = mat ? A1 : A0;
  const u16* __restrict__ B = mat ? B1 : B0;
  const int m0 = blockIdx.y * 128, n0 = blockIdx.x * 128;
  const int kb = sp * 2048;

  f32x4 acc[4][4];
  const f32x4 vzero = {0.f, 0.f, 0.f, 0.f};
#pragma unroll
  for (int a = 0; a < 4; ++a)
#pragma unroll
    for (int b = 0; b < 4; ++b) acc[a][b] = vzero;

#pragma unroll 1
  for (int kt = 0; kt < 32; ++kt){
    const int k0 = kb + kt*64;
#pragma unroll
    for (int it = 0; it < 4; ++it){
      int g = it*256 + tid;
      int r = g >> 3, gp = g & 7, gg = gp ^ (r & 7);
      async16(A + (size_t)(m0 + r)*32768 + k0 + gg*8, (char*)sA + (size_t)g*16);
    }
#pragma unroll
    for (int it = 0; it < 4; ++it){
      int g = it*256 + tid;
      int r = g >> 3, gp = g & 7, gg = gp ^ (r & 7);
      async16(B + (size_t)(n0 + r)*32768 + k0 + gg*8, (char*)sB + (size_t)g*16);
    }
    __syncthreads();
#pragma unroll
    for (int kk = 0; kk < 2; ++kk){
      bf16x8 af[4], bfv[4];
#pragma unroll
      for (int mt = 0; mt < 4; ++mt){
        int r = wm*64 + mt*16 + l15;
        int gg = (kk*4 + q) ^ (r & 7);
        af[mt] = *(const bf16x8*)(sA + (size_t)(r*8 + gg)*8);
      }
#pragma unroll
      for (int nt = 0; nt < 4; ++nt){
        int r = wn*64 + nt*16 + l15;
        int gg = (kk*4 + q) ^ (r & 7);
        bfv[nt] = *(const bf16x8*)(sB + (size_t)(r*8 + gg)*8);
      }
#pragma unroll
      for (int mt = 0; mt < 4; ++mt)
#pragma unroll
        for (int nt = 0; nt < 4; ++nt)
          acc[mt][nt] = __builtin_amdgcn_mfma_f32_16x16x32_bf16(af[mt], bfv[nt], acc[mt][nt], 0, 0, 0);
    }
    __syncthreads();
  }

  float* dst = part + (size_t)(mat*16 + sp)*262144;
#pragma unroll
  for (int mt = 0; mt < 4; ++mt)
#pragma unroll
    for (int nt = 0; nt < 4; ++nt){
      f32x4 v = acc[mt][nt];
      int n = wn*64 + nt*16 + l15;
      int mb = wm*64 + mt*16 + q*4;
      float* d = dst + (size_t)(m0 + mb)*512 + n0 + n;
      d[0] = v[0]; d[512] = v[1]; d[1024] = v[2]; d[1536] = v[3];
    }
}

// ---------------- fused LN(rec) -> relu(stim+recnorm) -> LN(act): one wave per row ----------
__global__ __launch_bounds__(256) void k_ln(const u16* __restrict__ SO, const u16* __restrict__ RO,
                                            const float* __restrict__ ga, const float* __restrict__ ba,
                                            const float* __restrict__ gr, const float* __restrict__ br,
                                            float* __restrict__ out){
  const int wid = threadIdx.x >> 6, lane = threadIdx.x & 63;
  const size_t b = (size_t)blockIdx.x*4 + wid;
  const int c = lane*8;
  float x[8], t[8];
  {
    u32x4 u = *(const u32x4*)(RO + b*512 + c);
#pragma unroll
    for (int i = 0; i < 4; ++i){
      u32 w = u[i];
      x[2*i]   = __uint_as_float(w << 16);
      x[2*i+1] = __uint_as_float(w & 0xFFFF0000u);
    }
  }
  float s = 0.f, ss = 0.f;
#pragma unroll
  for (int e = 0; e < 8; ++e){ s += x[e]; ss += x[e]*x[e]; }
  s = wave_sum(s); ss = wave_sum(ss);
  float mu = s*(1.f/512.f);
  float var = fmaxf(ss*(1.f/512.f) - mu*mu, 0.f);
  float rs = rsqrtf(var + 1e-5f);
  f32x4 g0 = *(const f32x4*)(gr + c), g1 = *(const f32x4*)(gr + c + 4);
  f32x4 h0 = *(const f32x4*)(br + c), h1 = *(const f32x4*)(br + c + 4);
  {
    u32x4 u = *(const u32x4*)(SO + b*512 + c);
    float so[8];
#pragma unroll
    for (int i = 0; i < 4; ++i){
      u32 w = u[i];
      so[2*i]   = __uint_as_float(w << 16);
      so[2*i+1] = __uint_as_float(w & 0xFFFF0000u);
    }
#pragma unroll
    for (int e = 0; e < 4; ++e) t[e]   = fmaxf(so[e]   + (x[e]  -mu)*rs*g0[e] + h0[e], 0.f);
#pragma unroll
    for (int e = 0; e < 4; ++e) t[4+e] = fmaxf(so[4+e] + (x[4+e]-mu)*rs*g1[e] + h1[e], 0.f);
  }
  float s2 = 0.f, ss2 = 0.f;
#pragma unroll
  for (int e = 0; e < 8; ++e){ s2 += t[e]; ss2 += t[e]*t[e]; }
  s2 = wave_sum(s2); ss2 = wave_sum(ss2);
  float mu2 = s2*(1.f/512.f);
  float var2 = fmaxf(ss2*(1.f/512.f) - mu2*mu2, 0.f);
  float rs2 = rsqrtf(var2 + 1e-5f);
  f32x4 G0 = *(const f32x4*)(ga + c), G1 = *(const f32x4*)(ga + c + 4);
  f32x4 H0 = *(const f32x4*)(ba + c), H1 = *(const f32x4*)(ba + c + 4);
  f32x4 o0, o1;
#pragma unroll
  for (int e = 0; e < 4; ++e){
    o0[e] = (t[e]   - mu2)*rs2*G0[e] + H0[e];
    o1[e] = (t[4+e] - mu2)*rs2*G1[e] + H1[e];
  }
  *(f32x4*)(out + b*512 + c)     = o0;
  *(f32x4*)(out + b*512 + c + 4) = o1;
}

// ---------------- finalize: newW = rownorm(W*(1-decay_i) + alpha_j * heb) ----------------
__global__ __launch_bounds__(256) void k_finalize(const float* __restrict__ W0, const float* __restrict__ W1,
                                                  const float* __restrict__ part,
                                                  const float* __restrict__ alpha, const float* __restrict__ decay,
                                                  float* __restrict__ out){
  const int i = blockIdx.x, mat = blockIdx.y;
  const int t = threadIdx.x;
  const float* Wm = mat ? W1 : W0;
  const float* pb = part + (size_t)mat*16*262144 + (size_t)i*512;
  const float dc = decay[i];
  float v[2], ssq = 0.f;
#pragma unroll
  for (int h = 0; h < 2; ++h){
    int j = t + h*256;
    float acc = 0.f;
#pragma unroll
    for (int sp = 0; sp < 16; ++sp) acc += pb[(size_t)sp*262144 + j];
    float val = Wm[(size_t)i*512 + j]*(1.f - dc) + alpha[j]*acc;
    v[h] = val; ssq += val*val;
  }
  float wsum = wave_sum(ssq);
  __shared__ float red[4];
  const int lane = t & 63, wid = t >> 6;
  if (lane == 0) red[wid] = wsum;
  __syncthreads();
  float tot = red[0] + red[1] + red[2] + red[3];
  float rn = 1.f / fmaxf(sqrtf(tot), 1e-12f);
  out[(size_t)mat*262144 + (size_t)i*512 + t]       = v[0]*rn;
  out[(size_t)mat*262144 + (size_t)i*512 + t + 256] = v[1]*rn;
}

extern "C" void kernel_launch(void* const* d_in, const int* in_sizes, int n_in,
                              void* d_out, int out_size, void* d_ws, size_t ws_size,
                              hipStream_t stream) {
  const float* S  = (const float*)d_in[0];
  const float* P  = (const float*)d_in[1];
  const float* W  = (const float*)d_in[2];
  const float* Wr = (const float*)d_in[3];
  const float* alpha = (const float*)d_in[4];
  const float* decay = (const float*)d_in[5];
  const float* ga = (const float*)d_in[6];
  const float* ba = (const float*)d_in[7];
  const float* gr = (const float*)d_in[8];
  const float* br = (const float*)d_in[9];
  float* out = (float*)d_out;

  char* ws = (char*)d_ws;
  u16* ST  = (u16*)(ws);                    // [512][32768] S^T bf16   32 MiB
  u16* PT  = (u16*)(ws + 33554432);         // [512][32768] P^T
  u16* SOT = (u16*)(ws + 67108864);         // [512][32768] (S@W)^T
  u16* ROT = (u16*)(ws + 100663296);        // [512][32768] (P@Wr)^T
  u16* SO  = (u16*)(ws + 134217728);        // [32768][512] S@W
  u16* RO  = (u16*)(ws + 167772160);        // [32768][512] P@Wr
  u16* Wt  = (u16*)(ws + 201326592);        // [512][512] W^T bf16
  u16* Wrt = (u16*)(ws + 201850880);        // [512][512] Wr^T bf16
  // split-K partials alias the SO region (SO/RO are dead after k_ln)
  float* part = (float*)(ws + 134217728);   // [2][16][512][512] fp32 = 32 MiB

  dim3 blk(256);
  // 1) transpose-converts
  k_tcvt<<<dim3(8, 512), blk, 0, stream>>>(S,  ST,  32768, 512);
  k_tcvt<<<dim3(8, 512), blk, 0, stream>>>(P,  PT,  32768, 512);
  k_tcvt<<<dim3(8, 8),   blk, 0, stream>>>(W,  Wt,  512, 512);
  k_tcvt<<<dim3(8, 8),   blk, 0, stream>>>(Wr, Wrt, 512, 512);
  // 2) forward GEMMs (dual-store natural + transposed)
  k_gemm_fwd<<<dim3(4, 256), blk, 0, stream>>>(S, Wt,  SO, SOT);
  k_gemm_fwd<<<dim3(4, 256), blk, 0, stream>>>(P, Wrt, RO, ROT);
  // 3) fused double layernorm -> final (reads SO/RO, then they are dead)
  k_ln<<<dim3(8192), blk, 0, stream>>>(SO, RO, ga, ba, gr, br, out);
  // 4) Hebbian update GEMMs, split-K=16, both matrices in one launch
  k_gemm_upd<<<dim3(4, 4, 32), blk, 0, stream>>>(ST, SOT, PT, ROT, part);
  // 5) reduce partials + scale + row L2-normalize
  k_finalize<<<dim3(512, 2), blk, 0, stream>>>(W, Wr, part, alpha, decay, out + 16777216);
}

// Round 2
// 372.654 us; speedup vs baseline: 1.0963x; 1.0963x over previous
//
#include <hip/hip_runtime.h>
#include <stdint.h>

typedef unsigned int u32;
typedef unsigned short u16;
typedef float  f32x4 __attribute__((ext_vector_type(4)));
typedef u32    u32x4 __attribute__((ext_vector_type(4)));
typedef __bf16 bf16x8 __attribute__((ext_vector_type(8)));

// fp32 -> bf16 RNE
static __device__ __forceinline__ u16 f2bf(float f){
  u32 u = __builtin_bit_cast(u32, f);
  return (u16)((u + 0x7FFFu + ((u >> 16) & 1u)) >> 16);
}

static __device__ __forceinline__ void async16(const void* g, void* l){
  __builtin_amdgcn_global_load_lds((const __attribute__((address_space(1))) u32*)g,
                                   (__attribute__((address_space(3))) u32*)l, 16, 0, 0);
}

static __device__ __forceinline__ float wave_sum(float v){
#pragma unroll
  for (int o = 32; o > 0; o >>= 1) v += __shfl_xor(v, o, 64);
  return v;
}

// ---------------- transpose + fp32->bf16 convert: dst[C][R] = src[R][C]; z picks tensor ----
__global__ __launch_bounds__(256) void k_tcvt(const float* __restrict__ s0, const float* __restrict__ s1,
                                              u16* __restrict__ d0, u16* __restrict__ d1,
                                              int R, int C){
  const float* __restrict__ src = blockIdx.z ? s1 : s0;
  u16* __restrict__ dst = blockIdx.z ? d1 : d0;
  __shared__ u16 lt[64*72];
  const int c0 = blockIdx.x * 64, r0 = blockIdx.y * 64;
  const int tid = threadIdx.x;
  const int rr = tid >> 4, c4 = tid & 15;
#pragma unroll
  for (int p = 0; p < 4; ++p){
    int r = rr + p*16;
    f32x4 f = *(const f32x4*)(src + (size_t)(r0 + r)*C + c0 + c4*4);
#pragma unroll
    for (int e = 0; e < 4; ++e) lt[(c4*4 + e)*72 + r] = f2bf(f[e]);
  }
  __syncthreads();
  const int c = tid >> 2, bg = tid & 3;
  const u32x4* lp = (const u32x4*)(lt + c*72 + bg*16);
  u32x4 w0 = lp[0], w1 = lp[1];
  u16* drow = dst + (size_t)(c0 + c)*R + r0 + bg*16;
  *(u32x4*)drow = w0;
  *(u32x4*)(drow + 8) = w1;
}

// ---------------- forward GEMM: C[m][n] = sum_k A32[m][k]*Bt[n][k], M=32768,N=512,K=512 ----
// 1D grid 1024, XCD-aware decode: x-siblings (sharing A slice) consecutive on one XCD.
__global__ __launch_bounds__(256) void k_gemm_fwd(const float* __restrict__ A,
                                                  const u16* __restrict__ Bt,
                                                  u16* __restrict__ Cn,
                                                  u16* __restrict__ Ct){
  __shared__ char smem[49152];
  float* sA = (float*)smem;            // [128 r][16 granules of 4 fp32], swizzle gp^(r&15)
  u16*   sB = (u16*)(smem + 32768);    // [128 r][8 granules of 8 bf16], swizzle gp^(r&7)
  const int tid = threadIdx.x;
  const int lane = tid & 63, wid = tid >> 6;
  const int wm = wid >> 1, wn = wid & 1;
  const int l15 = lane & 15, q = lane >> 4;
  const int id = blockIdx.x;
  const int c8 = id & 7, g = id >> 3;            // c8 = XCD slot
  const int yb = c8*32 + (g >> 2), xb = g & 3;   // y in [0,256), x in [0,4)
  const int m0 = yb * 128, n0 = xb * 128;

  f32x4 acc[4][4];
  const f32x4 vzero = {0.f, 0.f, 0.f, 0.f};
#pragma unroll
  for (int a = 0; a < 4; ++a)
#pragma unroll
    for (int b = 0; b < 4; ++b) acc[a][b] = vzero;

#pragma unroll 1
  for (int kt = 0; kt < 8; ++kt){
    const int k0 = kt*64;
#pragma unroll
    for (int it = 0; it < 8; ++it){        // A tile: 128x64 fp32 = 2048 x 16B
      int gg0 = it*256 + tid;
      int r = gg0 >> 4, gp = gg0 & 15;
      int gsw = gp ^ (r & 15);
      async16(A + (size_t)(m0 + r)*512 + k0 + gsw*4, (char*)sA + (size_t)gg0*16);
    }
#pragma unroll
    for (int it = 0; it < 4; ++it){        // B tile: 128x64 bf16 = 1024 x 16B
      int gg0 = it*256 + tid;
      int r = gg0 >> 3, gp = gg0 & 7;
      int gsw = gp ^ (r & 7);
      async16(Bt + (size_t)(n0 + r)*512 + k0 + gsw*8, (char*)sB + (size_t)gg0*16);
    }
    __syncthreads();
#pragma unroll
    for (int kk = 0; kk < 2; ++kk){
      bf16x8 af[4], bfv[4];
#pragma unroll
      for (int mt = 0; mt < 4; ++mt){
        int r = wm*64 + mt*16 + l15;
        int d0i = (kk*8 + q*2) ^ (r & 15);
        int d1i = (kk*8 + q*2 + 1) ^ (r & 15);
        f32x4 f0 = *(const f32x4*)(sA + (size_t)(r*16 + d0i)*4);
        f32x4 f1 = *(const f32x4*)(sA + (size_t)(r*16 + d1i)*4);
        bf16x8 a;
        a[0]=(__bf16)f0[0]; a[1]=(__bf16)f0[1]; a[2]=(__bf16)f0[2]; a[3]=(__bf16)f0[3];
        a[4]=(__bf16)f1[0]; a[5]=(__bf16)f1[1]; a[6]=(__bf16)f1[2]; a[7]=(__bf16)f1[3];
        af[mt] = a;
      }
#pragma unroll
      for (int nt = 0; nt < 4; ++nt){
        int r = wn*64 + nt*16 + l15;
        int gsw = (kk*4 + q) ^ (r & 7);
        bfv[nt] = *(const bf16x8*)(sB + (size_t)(r*8 + gsw)*8);
      }
#pragma unroll
      for (int mt = 0; mt < 4; ++mt)
#pragma unroll
        for (int nt = 0; nt < 4; ++nt)
          acc[mt][nt] = __builtin_amdgcn_mfma_f32_16x16x32_bf16(af[mt], bfv[nt], acc[mt][nt], 0, 0, 0);
    }
    __syncthreads();
  }

  // epilogue: natural bf16 store + transposed store via LDS round-trip
  u16* lt = (u16*)smem;   // [128 n][136 m] bf16
#pragma unroll
  for (int mt = 0; mt < 4; ++mt)
#pragma unroll
    for (int nt = 0; nt < 4; ++nt){
      f32x4 v = acc[mt][nt];
      u16 b0 = f2bf(v[0]), b1 = f2bf(v[1]), b2 = f2bf(v[2]), b3 = f2bf(v[3]);
      int n = wn*64 + nt*16 + l15;
      int mb = wm*64 + mt*16 + q*4;
      u16* cn = Cn + (size_t)(m0 + mb)*512 + n0 + n;
      cn[0] = b0; cn[512] = b1; cn[1024] = b2; cn[1536] = b3;
      *(u32*)(lt + n*136 + mb)     = (u32)b0 | ((u32)b1 << 16);
      *(u32*)(lt + n*136 + mb + 2) = (u32)b2 | ((u32)b3 << 16);
    }
  __syncthreads();
#pragma unroll
  for (int p = 0; p < 8; ++p){
    int gg0 = p*256 + tid;
    int n = gg0 >> 4, mg = gg0 & 15;
    u32x4 w = *(const u32x4*)(lt + n*136 + mg*8);
    *(u32x4*)(Ct + (size_t)(n0 + n)*32768 + m0 + mg*8) = w;
  }
}

// ---------------- update GEMM: C[i][j] = sum_b A[i][b]*B[j][b]; M=N=512, K=32768, split-K=32 ----
// 1D grid 1024, XCD-aware decode: 8 (mat,sp) K-chunks per XCD, xy-siblings co-located.
__global__ __launch_bounds__(256) void k_gemm_upd(const u16* __restrict__ A0, const u16* __restrict__ B0,
                                                  const u16* __restrict__ A1, const u16* __restrict__ B1,
                                                  float* __restrict__ part){
  __shared__ char smem[32768];
  u16* sA = (u16*)smem;
  u16* sB = (u16*)(smem + 16384);
  const int tid = threadIdx.x;
  const int lane = tid & 63, wid = tid >> 6;
  const int wm = wid >> 1, wn = wid & 1;
  const int l15 = lane & 15, q = lane >> 4;
  const int id = blockIdx.x;
  const int c8 = id & 7, g = id >> 3;          // per-XCD stream of 128 blocks
  const int zz = c8*8 + (g >> 4);              // (mat,sp) chunk in [0,64)
  const int xb = g & 3, yb = (g >> 2) & 3;
  const int mat = zz >> 5, sp = zz & 31;
  const u16* __restrict__ A = mat ? A1 : A0;
  const u16* __restrict__ B = mat ? B1 : B0;
  const int m0 = yb * 128, n0 = xb * 128;
  const int kb = sp * 1024;

  f32x4 acc[4][4];
  const f32x4 vzero = {0.f, 0.f, 0.f, 0.f};
#pragma unroll
  for (int a = 0; a < 4; ++a)
#pragma unroll
    for (int b = 0; b < 4; ++b) acc[a][b] = vzero;

#pragma unroll 1
  for (int kt = 0; kt < 16; ++kt){
    const int k0 = kb + kt*64;
#pragma unroll
    for (int it = 0; it < 4; ++it){
      int gg0 = it*256 + tid;
      int r = gg0 >> 3, gp = gg0 & 7, gsw = gp ^ (r & 7);
      async16(A + (size_t)(m0 + r)*32768 + k0 + gsw*8, (char*)sA + (size_t)gg0*16);
    }
#pragma unroll
    for (int it = 0; it < 4; ++it){
      int gg0 = it*256 + tid;
      int r = gg0 >> 3, gp = gg0 & 7, gsw = gp ^ (r & 7);
      async16(B + (size_t)(n0 + r)*32768 + k0 + gsw*8, (char*)sB + (size_t)gg0*16);
    }
    __syncthreads();
#pragma unroll
    for (int kk = 0; kk < 2; ++kk){
      bf16x8 af[4], bfv[4];
#pragma unroll
      for (int mt = 0; mt < 4; ++mt){
        int r = wm*64 + mt*16 + l15;
        int gsw = (kk*4 + q) ^ (r & 7);
        af[mt] = *(const bf16x8*)(sA + (size_t)(r*8 + gsw)*8);
      }
#pragma unroll
      for (int nt = 0; nt < 4; ++nt){
        int r = wn*64 + nt*16 + l15;
        int gsw = (kk*4 + q) ^ (r & 7);
        bfv[nt] = *(const bf16x8*)(sB + (size_t)(r*8 + gsw)*8);
      }
#pragma unroll
      for (int mt = 0; mt < 4; ++mt)
#pragma unroll
        for (int nt = 0; nt < 4; ++nt)
          acc[mt][nt] = __builtin_amdgcn_mfma_f32_16x16x32_bf16(af[mt], bfv[nt], acc[mt][nt], 0, 0, 0);
    }
    __syncthreads();
  }

  float* dst = part + (size_t)(mat*32 + sp)*262144;
#pragma unroll
  for (int mt = 0; mt < 4; ++mt)
#pragma unroll
    for (int nt = 0; nt < 4; ++nt){
      f32x4 v = acc[mt][nt];
      int n = wn*64 + nt*16 + l15;
      int mb = wm*64 + mt*16 + q*4;
      float* d = dst + (size_t)(m0 + mb)*512 + n0 + n;
      d[0] = v[0]; d[512] = v[1]; d[1024] = v[2]; d[1536] = v[3];
    }
}

// ---------------- fused LN(rec) -> relu(stim+recnorm) -> LN(act): one wave per row ----------
__global__ __launch_bounds__(256) void k_ln(const u16* __restrict__ SO, const u16* __restrict__ RO,
                                            const float* __restrict__ ga, const float* __restrict__ ba,
                                            const float* __restrict__ gr, const float* __restrict__ br,
                                            float* __restrict__ out){
  const int wid = threadIdx.x >> 6, lane = threadIdx.x & 63;
  const size_t b = (size_t)blockIdx.x*4 + wid;
  const int c = lane*8;
  float x[8], t[8];
  {
    u32x4 u = *(const u32x4*)(RO + b*512 + c);
#pragma unroll
    for (int i = 0; i < 4; ++i){
      u32 w = u[i];
      x[2*i]   = __uint_as_float(w << 16);
      x[2*i+1] = __uint_as_float(w & 0xFFFF0000u);
    }
  }
  float s = 0.f, ss = 0.f;
#pragma unroll
  for (int e = 0; e < 8; ++e){ s += x[e]; ss += x[e]*x[e]; }
  s = wave_sum(s); ss = wave_sum(ss);
  float mu = s*(1.f/512.f);
  float var = fmaxf(ss*(1.f/512.f) - mu*mu, 0.f);
  float rs = rsqrtf(var + 1e-5f);
  f32x4 g0 = *(const f32x4*)(gr + c), g1 = *(const f32x4*)(gr + c + 4);
  f32x4 h0 = *(const f32x4*)(br + c), h1 = *(const f32x4*)(br + c + 4);
  {
    u32x4 u = *(const u32x4*)(SO + b*512 + c);
    float so[8];
#pragma unroll
    for (int i = 0; i < 4; ++i){
      u32 w = u[i];
      so[2*i]   = __uint_as_float(w << 16);
      so[2*i+1] = __uint_as_float(w & 0xFFFF0000u);
    }
#pragma unroll
    for (int e = 0; e < 4; ++e) t[e]   = fmaxf(so[e]   + (x[e]  -mu)*rs*g0[e] + h0[e], 0.f);
#pragma unroll
    for (int e = 0; e < 4; ++e) t[4+e] = fmaxf(so[4+e] + (x[4+e]-mu)*rs*g1[e] + h1[e], 0.f);
  }
  float s2 = 0.f, ss2 = 0.f;
#pragma unroll
  for (int e = 0; e < 8; ++e){ s2 += t[e]; ss2 += t[e]*t[e]; }
  s2 = wave_sum(s2); ss2 = wave_sum(ss2);
  float mu2 = s2*(1.f/512.f);
  float var2 = fmaxf(ss2*(1.f/512.f) - mu2*mu2, 0.f);
  float rs2 = rsqrtf(var2 + 1e-5f);
  f32x4 G0 = *(const f32x4*)(ga + c), G1 = *(const f32x4*)(ga + c + 4);
  f32x4 H0 = *(const f32x4*)(ba + c), H1 = *(const f32x4*)(ba + c + 4);
  f32x4 o0, o1;
#pragma unroll
  for (int e = 0; e < 4; ++e){
    o0[e] = (t[e]   - mu2)*rs2*G0[e] + H0[e];
    o1[e] = (t[4+e] - mu2)*rs2*G1[e] + H1[e];
  }
  *(f32x4*)(out + b*512 + c)     = o0;
  *(f32x4*)(out + b*512 + c + 4) = o1;
}

// ---------------- finalize: newW = rownorm(W*(1-decay_i) + alpha_j * heb) ----------------
__global__ __launch_bounds__(256) void k_finalize(const float* __restrict__ W0, const float* __restrict__ W1,
                                                  const float* __restrict__ part,
                                                  const float* __restrict__ alpha, const float* __restrict__ decay,
                                                  float* __restrict__ out){
  const int i = blockIdx.x, mat = blockIdx.y;
  const int t = threadIdx.x;
  const float* Wm = mat ? W1 : W0;
  const float* pb = part + (size_t)mat*32*262144 + (size_t)i*512;
  const float dc = decay[i];
  float v[2], ssq = 0.f;
#pragma unroll
  for (int h = 0; h < 2; ++h){
    int j = t + h*256;
    float acc = 0.f;
#pragma unroll
    for (int sp = 0; sp < 32; ++sp) acc += pb[(size_t)sp*262144 + j];
    float val = Wm[(size_t)i*512 + j]*(1.f - dc) + alpha[j]*acc;
    v[h] = val; ssq += val*val;
  }
  float wsum = wave_sum(ssq);
  __shared__ float red[4];
  const int lane = t & 63, wid = t >> 6;
  if (lane == 0) red[wid] = wsum;
  __syncthreads();
  float tot = red[0] + red[1] + red[2] + red[3];
  float rn = 1.f / fmaxf(sqrtf(tot), 1e-12f);
  out[(size_t)mat*262144 + (size_t)i*512 + t]       = v[0]*rn;
  out[(size_t)mat*262144 + (size_t)i*512 + t + 256] = v[1]*rn;
}

extern "C" void kernel_launch(void* const* d_in, const int* in_sizes, int n_in,
                              void* d_out, int out_size, void* d_ws, size_t ws_size,
                              hipStream_t stream) {
  const float* S  = (const float*)d_in[0];
  const float* P  = (const float*)d_in[1];
  const float* W  = (const float*)d_in[2];
  const float* Wr = (const float*)d_in[3];
  const float* alpha = (const float*)d_in[4];
  const float* decay = (const float*)d_in[5];
  const float* ga = (const float*)d_in[6];
  const float* ba = (const float*)d_in[7];
  const float* gr = (const float*)d_in[8];
  const float* br = (const float*)d_in[9];
  float* out = (float*)d_out;

  char* ws = (char*)d_ws;
  u16* ST  = (u16*)(ws);                    // [512][32768] S^T bf16   32 MiB
  u16* PT  = (u16*)(ws + 33554432);         // [512][32768] P^T
  u16* SOT = (u16*)(ws + 67108864);         // [512][32768] (S@W)^T
  u16* ROT = (u16*)(ws + 100663296);        // [512][32768] (P@Wr)^T
  u16* SO  = (u16*)(ws + 134217728);        // [32768][512] S@W
  u16* RO  = (u16*)(ws + 167772160);        // [32768][512] P@Wr
  u16* Wt  = (u16*)(ws + 201326592);        // [512][512] W^T bf16
  u16* Wrt = (u16*)(ws + 201850880);        // [512][512] Wr^T bf16
  // split-K=32 partials alias the SO/RO region (dead after k_ln): 2*32*512*512*4 = 64 MiB exact
  float* part = (float*)(ws + 134217728);

  dim3 blk(256);
  // 1) transpose-converts (S+P merged; W+Wr merged)
  k_tcvt<<<dim3(8, 512, 2), blk, 0, stream>>>(S, P, ST, PT, 32768, 512);
  k_tcvt<<<dim3(8, 8, 2),   blk, 0, stream>>>(W, Wr, Wt, Wrt, 512, 512);
  // 2) forward GEMMs (dual-store natural + transposed), XCD-swizzled 1D grid
  k_gemm_fwd<<<dim3(1024), blk, 0, stream>>>(S, Wt,  SO, SOT);
  k_gemm_fwd<<<dim3(1024), blk, 0, stream>>>(P, Wrt, RO, ROT);
  // 3) fused double layernorm -> final (reads SO/RO, then they are dead)
  k_ln<<<dim3(8192), blk, 0, stream>>>(SO, RO, ga, ba, gr, br, out);
  // 4) Hebbian update GEMMs, split-K=32, both matrices, XCD-swizzled 1D grid
  k_gemm_upd<<<dim3(1024), blk, 0, stream>>>(ST, SOT, PT, ROT, part);
  // 5) reduce partials + scale + row L2-normalize
  k_finalize<<<dim3(512, 2), blk, 0, stream>>>(W, Wr, part, alpha, decay, out + 16777216);
}

// Round 4
// 324.101 us; speedup vs baseline: 1.2605x; 1.1498x over previous
//
#include <hip/hip_runtime.h>
#include <stdint.h>

typedef unsigned int u32;
typedef unsigned short u16;
typedef float  f32x4 __attribute__((ext_vector_type(4)));
typedef u32    u32x4 __attribute__((ext_vector_type(4)));
typedef __bf16 bf16x8 __attribute__((ext_vector_type(8)));

// fp32 -> bf16 RNE
static __device__ __forceinline__ u16 f2bf(float f){
  u32 u = __builtin_bit_cast(u32, f);
  return (u16)((u + 0x7FFFu + ((u >> 16) & 1u)) >> 16);
}

static __device__ __forceinline__ void async16(const void* g, void* l){
  __builtin_amdgcn_global_load_lds((const __attribute__((address_space(1))) u32*)g,
                                   (__attribute__((address_space(3))) u32*)l, 16, 0, 0);
}

static __device__ __forceinline__ float wave_sum(float v){
#pragma unroll
  for (int o = 32; o > 0; o >>= 1) v += __shfl_xor(v, o, 64);
  return v;
}

// ---------------- pure convert fp32 -> bf16 natural (S,P) ----------------
__global__ __launch_bounds__(256) void k_cvt(const float* __restrict__ s0, const float* __restrict__ s1,
                                             u16* __restrict__ d0, u16* __restrict__ d1){
  const float* __restrict__ src = blockIdx.y ? s1 : s0;
  u16* __restrict__ dst = blockIdx.y ? d1 : d0;
  size_t i = ((size_t)blockIdx.x*256 + threadIdx.x) * 8;
  f32x4 a = *(const f32x4*)(src + i);
  f32x4 b = *(const f32x4*)(src + i + 4);
  u32x4 w;
  w[0] = (u32)f2bf(a[0]) | ((u32)f2bf(a[1]) << 16);
  w[1] = (u32)f2bf(a[2]) | ((u32)f2bf(a[3]) << 16);
  w[2] = (u32)f2bf(b[0]) | ((u32)f2bf(b[1]) << 16);
  w[3] = (u32)f2bf(b[2]) | ((u32)f2bf(b[3]) << 16);
  *(u32x4*)(dst + i) = w;
}

// ---------------- transpose + convert for W/Wr: dst[C][R] = src[R][C] ----------------
__global__ __launch_bounds__(256) void k_tcvt(const float* __restrict__ s0, const float* __restrict__ s1,
                                              u16* __restrict__ d0, u16* __restrict__ d1,
                                              int R, int C){
  const float* __restrict__ src = blockIdx.z ? s1 : s0;
  u16* __restrict__ dst = blockIdx.z ? d1 : d0;
  __shared__ u16 lt[64*72];
  const int c0 = blockIdx.x * 64, r0 = blockIdx.y * 64;
  const int tid = threadIdx.x;
  const int rr = tid >> 4, c4 = tid & 15;
#pragma unroll
  for (int p = 0; p < 4; ++p){
    int r = rr + p*16;
    f32x4 f = *(const f32x4*)(src + (size_t)(r0 + r)*C + c0 + c4*4);
#pragma unroll
    for (int e = 0; e < 4; ++e) lt[(c4*4 + e)*72 + r] = f2bf(f[e]);
  }
  __syncthreads();
  const int c = tid >> 2, bg = tid & 3;
  const u32x4* lp = (const u32x4*)(lt + c*72 + bg*16);
  u32x4 w0 = lp[0], w1 = lp[1];
  u16* drow = dst + (size_t)(c0 + c)*R + r0 + bg*16;
  *(u32x4*)drow = w0;
  *(u32x4*)(drow + 8) = w1;
}

// ---------------- forward GEMM (merged S&P): C[m][n] = sum_k A[m][k]*Bt[n][k] ----------------
// Tile 256x128, BK=64, 512 threads. A bf16 natural; dual-store Cn + Ct.
__global__ __launch_bounds__(512) void k_gemm_fwd(const u16* __restrict__ SN, const u16* __restrict__ PN,
                                                  const u16* __restrict__ Wt, const u16* __restrict__ Wrt,
                                                  u16* __restrict__ SO, u16* __restrict__ RO,
                                                  u16* __restrict__ SOT, u16* __restrict__ ROT){
  __shared__ char smem[67584];
  u16* sA = (u16*)smem;                 // [256 r][8 granules of 8 bf16], swizzle gp^(r&7)
  u16* sB = (u16*)(smem + 32768);       // [128 r][8 granules], swizzle gp^(r&7)
  const int tid = threadIdx.x;
  const int lane = tid & 63, wid = tid >> 6;
  const int wm = wid >> 1, wn = wid & 1;          // 4 x 2 wave grid
  const int l15 = lane & 15, q = lane >> 4;
  const int id = blockIdx.x;
  const int c8 = id & 7, g = id >> 3;             // 128 blocks per XCD
  const int sel = g >> 6, h = g & 63;
  const int yb = c8*16 + (h >> 2), xb = h & 3;
  const int m0 = yb * 256, n0 = xb * 128;
  const u16* __restrict__ A  = sel ? PN  : SN;
  const u16* __restrict__ Bt = sel ? Wrt : Wt;
  u16* __restrict__ Cn = sel ? RO  : SO;
  u16* __restrict__ Ct = sel ? ROT : SOT;

  f32x4 acc[4][4];
  const f32x4 vzero = {0.f, 0.f, 0.f, 0.f};
#pragma unroll
  for (int a = 0; a < 4; ++a)
#pragma unroll
    for (int b = 0; b < 4; ++b) acc[a][b] = vzero;

#pragma unroll 1
  for (int kt = 0; kt < 8; ++kt){
    const int k0 = kt*64;
#pragma unroll
    for (int it = 0; it < 4; ++it){     // A: 256x64 bf16 = 2048 granules
      int gg0 = it*512 + tid;
      int r = gg0 >> 3, gp = gg0 & 7, gsw = gp ^ (r & 7);
      async16(A + (size_t)(m0 + r)*512 + k0 + gsw*8, (char*)sA + (size_t)gg0*16);
    }
#pragma unroll
    for (int it = 0; it < 2; ++it){     // B: 128x64 bf16 = 1024 granules
      int gg0 = it*512 + tid;
      int r = gg0 >> 3, gp = gg0 & 7, gsw = gp ^ (r & 7);
      async16(Bt + (size_t)(n0 + r)*512 + k0 + gsw*8, (char*)sB + (size_t)gg0*16);
    }
    __syncthreads();
#pragma unroll
    for (int kk = 0; kk < 2; ++kk){
      bf16x8 af[4], bfv[4];
#pragma unroll
      for (int mt = 0; mt < 4; ++mt){
        int r = wm*64 + mt*16 + l15;
        int gsw = (kk*4 + q) ^ (r & 7);
        af[mt] = *(const bf16x8*)(sA + (size_t)(r*8 + gsw)*8);
      }
#pragma unroll
      for (int nt = 0; nt < 4; ++nt){
        int r = wn*64 + nt*16 + l15;
        int gsw = (kk*4 + q) ^ (r & 7);
        bfv[nt] = *(const bf16x8*)(sB + (size_t)(r*8 + gsw)*8);
      }
#pragma unroll
      for (int mt = 0; mt < 4; ++mt)
#pragma unroll
        for (int nt = 0; nt < 4; ++nt)
          acc[mt][nt] = __builtin_amdgcn_mfma_f32_16x16x32_bf16(af[mt], bfv[nt], acc[mt][nt], 0, 0, 0);
    }
    __syncthreads();
  }

  // epilogue: natural store + transposed store via LDS round-trip
  u16* lt = (u16*)smem;   // [128 n][264 m] bf16
#pragma unroll
  for (int mt = 0; mt < 4; ++mt)
#pragma unroll
    for (int nt = 0; nt < 4; ++nt){
      f32x4 v = acc[mt][nt];
      u16 b0 = f2bf(v[0]), b1 = f2bf(v[1]), b2 = f2bf(v[2]), b3 = f2bf(v[3]);
      int n = wn*64 + nt*16 + l15;
      int mb = wm*64 + mt*16 + q*4;
      u16* cn = Cn + (size_t)(m0 + mb)*512 + n0 + n;
      cn[0] = b0; cn[512] = b1; cn[1024] = b2; cn[1536] = b3;
      *(u32*)(lt + n*264 + mb)     = (u32)b0 | ((u32)b1 << 16);
      *(u32*)(lt + n*264 + mb + 2) = (u32)b2 | ((u32)b3 << 16);
    }
  __syncthreads();
#pragma unroll
  for (int p = 0; p < 8; ++p){
    int gg0 = p*512 + tid;
    int n = gg0 >> 5, mg = gg0 & 31;
    u32x4 w = *(const u32x4*)(lt + n*264 + mg*8);
    *(u32x4*)(Ct + (size_t)(n0 + n)*32768 + m0 + mg*8) = w;
  }
}

// ---------------- update GEMM: C[i][j] = sum_b A[b][i]*B[j][b]; tile 128x256, split-K=32 ----
// A natural bf16 (SN/PN) with in-LDS transpose; B transposed (SOT/ROT).
// LDS map: sAn [0,16384) = 64k x 128i bf16; sAt [16384,34816) = 128i x 36 u32;
//          sB [34816,67584) = 256j x 64k bf16 (32768 B). Total 67584 (R3 bug: sB overflowed 51200).
__global__ __launch_bounds__(512) void k_gemm_upd(const u16* __restrict__ A0, const u16* __restrict__ B0,
                                                  const u16* __restrict__ A1, const u16* __restrict__ B1,
                                                  float* __restrict__ part){
  __shared__ char smem[67584];
  char* sAn = smem;
  u32*  sAt = (u32*)(smem + 16384);
  u16*  sB  = (u16*)(smem + 34816);
  const int tid = threadIdx.x;
  const int lane = tid & 63, wid = tid >> 6;
  const int wm = wid >> 2, wn = wid & 3;          // 2 x 4 wave grid (128 m x 256 n)
  const int l15 = lane & 15, q = lane >> 4;
  const int id = blockIdx.x;
  const int c8 = id & 7, g = id >> 3;             // 64 blocks per XCD
  const int zz = c8*8 + (g >> 3);                 // (mat,sp) in [0,64)
  const int xy = g & 7;
  const int mat = zz >> 5, sp = zz & 31;
  const int yb = xy & 3, xb = xy >> 2;
  const u16* __restrict__ A = mat ? A1 : A0;
  const u16* __restrict__ B = mat ? B1 : B0;
  const int m0 = yb * 128, n0 = xb * 256;
  const int kb = sp * 1024;
  // transpose assignment: lane-local chunk/pair
  const int base_c = tid >> 5, pr = tid & 31;
  const int ce = (base_c + pr) & 15;

  f32x4 acc[4][4];
  const f32x4 vzero = {0.f, 0.f, 0.f, 0.f};
#pragma unroll
  for (int a = 0; a < 4; ++a)
#pragma unroll
    for (int b = 0; b < 4; ++b) acc[a][b] = vzero;

#pragma unroll 1
  for (int kt = 0; kt < 16; ++kt){
    const int k0 = kb + kt*64;
#pragma unroll
    for (int it = 0; it < 2; ++it){     // A natural: 64 rows x 128 cols bf16 = 1024 granules
      int gg0 = it*512 + tid;
      int r = gg0 >> 4, gp = gg0 & 15;  // 16 granules per 128-col row, plain layout
      async16(A + (size_t)(k0 + r)*512 + m0 + gp*8, sAn + (size_t)gg0*16);
    }
#pragma unroll
    for (int it = 0; it < 4; ++it){     // B: 256 rows x 64 k bf16 = 2048 granules
      int gg0 = it*512 + tid;
      int r = gg0 >> 3, gp = gg0 & 7, gsw = gp ^ (r & 7);
      async16(B + (size_t)(n0 + r)*32768 + k0 + gsw*8, (char*)sB + (size_t)gg0*16);
    }
    __syncthreads();
    // in-LDS transpose of A: [64 k][128 i] -> sAt[i][pr] (k-pairs packed in u32)
    {
      u32x4 r0 = *(const u32x4*)(sAn + (size_t)(2*pr)*256 + ce*16);
      u32x4 r1 = *(const u32x4*)(sAn + (size_t)(2*pr)*256 + 256 + ce*16);
#pragma unroll
      for (int e = 0; e < 4; ++e){
        u32 lo = r0[e], hi = r1[e];
        sAt[(ce*8 + 2*e    )*36 + pr] = (lo & 0xFFFFu) | (hi << 16);
        sAt[(ce*8 + 2*e + 1)*36 + pr] = (lo >> 16) | (hi & 0xFFFF0000u);
      }
    }
    __syncthreads();
#pragma unroll
    for (int kk = 0; kk < 2; ++kk){
      bf16x8 af[4], bfv[4];
#pragma unroll
      for (int mt = 0; mt < 4; ++mt){
        int r = wm*64 + mt*16 + l15;
        af[mt] = *(const bf16x8*)(sAt + (size_t)r*36 + kk*16 + q*4);
      }
#pragma unroll
      for (int nt = 0; nt < 4; ++nt){
        int r = wn*64 + nt*16 + l15;
        int gsw = (kk*4 + q) ^ (r & 7);
        bfv[nt] = *(const bf16x8*)(sB + (size_t)(r*8 + gsw)*8);
      }
#pragma unroll
      for (int mt = 0; mt < 4; ++mt)
#pragma unroll
        for (int nt = 0; nt < 4; ++nt)
          acc[mt][nt] = __builtin_amdgcn_mfma_f32_16x16x32_bf16(af[mt], bfv[nt], acc[mt][nt], 0, 0, 0);
    }
    __syncthreads();
  }

  float* dst = part + (size_t)(mat*32 + sp)*262144;
#pragma unroll
  for (int mt = 0; mt < 4; ++mt)
#pragma unroll
    for (int nt = 0; nt < 4; ++nt){
      f32x4 v = acc[mt][nt];
      int n = wn*64 + nt*16 + l15;
      int mb = wm*64 + mt*16 + q*4;
      float* d = dst + (size_t)(m0 + mb)*512 + n0 + n;
      d[0] = v[0]; d[512] = v[1]; d[1024] = v[2]; d[1536] = v[3];
    }
}

// ---------------- fused LN(rec) -> relu(stim+recnorm) -> LN(act): one wave per row ----------
__global__ __launch_bounds__(256) void k_ln(const u16* __restrict__ SO, const u16* __restrict__ RO,
                                            const float* __restrict__ ga, const float* __restrict__ ba,
                                            const float* __restrict__ gr, const float* __restrict__ br,
                                            float* __restrict__ out){
  const int wid = threadIdx.x >> 6, lane = threadIdx.x & 63;
  const size_t b = (size_t)blockIdx.x*4 + wid;
  const int c = lane*8;
  float x[8], t[8];
  {
    u32x4 u = *(const u32x4*)(RO + b*512 + c);
#pragma unroll
    for (int i = 0; i < 4; ++i){
      u32 w = u[i];
      x[2*i]   = __uint_as_float(w << 16);
      x[2*i+1] = __uint_as_float(w & 0xFFFF0000u);
    }
  }
  float s = 0.f, ss = 0.f;
#pragma unroll
  for (int e = 0; e < 8; ++e){ s += x[e]; ss += x[e]*x[e]; }
  s = wave_sum(s); ss = wave_sum(ss);
  float mu = s*(1.f/512.f);
  float var = fmaxf(ss*(1.f/512.f) - mu*mu, 0.f);
  float rs = rsqrtf(var + 1e-5f);
  f32x4 g0 = *(const f32x4*)(gr + c), g1 = *(const f32x4*)(gr + c + 4);
  f32x4 h0 = *(const f32x4*)(br + c), h1 = *(const f32x4*)(br + c + 4);
  {
    u32x4 u = *(const u32x4*)(SO + b*512 + c);
    float so[8];
#pragma unroll
    for (int i = 0; i < 4; ++i){
      u32 w = u[i];
      so[2*i]   = __uint_as_float(w << 16);
      so[2*i+1] = __uint_as_float(w & 0xFFFF0000u);
    }
#pragma unroll
    for (int e = 0; e < 4; ++e) t[e]   = fmaxf(so[e]   + (x[e]  -mu)*rs*g0[e] + h0[e], 0.f);
#pragma unroll
    for (int e = 0; e < 4; ++e) t[4+e] = fmaxf(so[4+e] + (x[4+e]-mu)*rs*g1[e] + h1[e], 0.f);
  }
  float s2 = 0.f, ss2 = 0.f;
#pragma unroll
  for (int e = 0; e < 8; ++e){ s2 += t[e]; ss2 += t[e]*t[e]; }
  s2 = wave_sum(s2); ss2 = wave_sum(ss2);
  float mu2 = s2*(1.f/512.f);
  float var2 = fmaxf(ss2*(1.f/512.f) - mu2*mu2, 0.f);
  float rs2 = rsqrtf(var2 + 1e-5f);
  f32x4 G0 = *(const f32x4*)(ga + c), G1 = *(const f32x4*)(ga + c + 4);
  f32x4 H0 = *(const f32x4*)(ba + c), H1 = *(const f32x4*)(ba + c + 4);
  f32x4 o0, o1;
#pragma unroll
  for (int e = 0; e < 4; ++e){
    o0[e] = (t[e]   - mu2)*rs2*G0[e] + H0[e];
    o1[e] = (t[4+e] - mu2)*rs2*G1[e] + H1[e];
  }
  *(f32x4*)(out + b*512 + c)     = o0;
  *(f32x4*)(out + b*512 + c + 4) = o1;
}

// ---------------- finalize: newW = rownorm(W*(1-decay_i) + alpha_j * heb) ----------------
__global__ __launch_bounds__(256) void k_finalize(const float* __restrict__ W0, const float* __restrict__ W1,
                                                  const float* __restrict__ part,
                                                  const float* __restrict__ alpha, const float* __restrict__ decay,
                                                  float* __restrict__ out){
  const int i = blockIdx.x, mat = blockIdx.y;
  const int t = threadIdx.x;
  const float* Wm = mat ? W1 : W0;
  const float* pb = part + (size_t)mat*32*262144 + (size_t)i*512;
  const float dc = decay[i];
  float v[2], ssq = 0.f;
#pragma unroll
  for (int h = 0; h < 2; ++h){
    int j = t + h*256;
    float acc = 0.f;
#pragma unroll
    for (int sp = 0; sp < 32; ++sp) acc += pb[(size_t)sp*262144 + j];
    float val = Wm[(size_t)i*512 + j]*(1.f - dc) + alpha[j]*acc;
    v[h] = val; ssq += val*val;
  }
  float wsum = wave_sum(ssq);
  __shared__ float red[4];
  const int lane = t & 63, wid = t >> 6;
  if (lane == 0) red[wid] = wsum;
  __syncthreads();
  float tot = red[0] + red[1] + red[2] + red[3];
  float rn = 1.f / fmaxf(sqrtf(tot), 1e-12f);
  out[(size_t)mat*262144 + (size_t)i*512 + t]       = v[0]*rn;
  out[(size_t)mat*262144 + (size_t)i*512 + t + 256] = v[1]*rn;
}

extern "C" void kernel_launch(void* const* d_in, const int* in_sizes, int n_in,
                              void* d_out, int out_size, void* d_ws, size_t ws_size,
                              hipStream_t stream) {
  const float* S  = (const float*)d_in[0];
  const float* P  = (const float*)d_in[1];
  const float* W  = (const float*)d_in[2];
  const float* Wr = (const float*)d_in[3];
  const float* alpha = (const float*)d_in[4];
  const float* decay = (const float*)d_in[5];
  const float* ga = (const float*)d_in[6];
  const float* ba = (const float*)d_in[7];
  const float* gr = (const float*)d_in[8];
  const float* br = (const float*)d_in[9];
  float* out = (float*)d_out;

  char* ws = (char*)d_ws;
  u16* SN  = (u16*)(ws);                    // [32768][512] S bf16 natural   32 MiB
  u16* PN  = (u16*)(ws + 33554432);         // [32768][512] P bf16 natural
  u16* SOT = (u16*)(ws + 67108864);         // [512][32768] (S@W)^T
  u16* ROT = (u16*)(ws + 100663296);        // [512][32768] (P@Wr)^T
  u16* SO  = (u16*)(ws + 134217728);        // [32768][512] S@W
  u16* RO  = (u16*)(ws + 167772160);        // [32768][512] P@Wr
  u16* Wt  = (u16*)(ws + 201326592);        // [512][512] W^T bf16
  u16* Wrt = (u16*)(ws + 201850880);        // [512][512] Wr^T bf16
  // split-K=32 partials alias SO/RO (dead after k_ln): 2*32*512*512*4 = 64 MiB exact
  float* part = (float*)(ws + 134217728);

  // 1) converts
  k_cvt<<<dim3(8192, 2), dim3(256), 0, stream>>>(S, P, SN, PN);
  k_tcvt<<<dim3(8, 8, 2), dim3(256), 0, stream>>>(W, Wr, Wt, Wrt, 512, 512);
  // 2) forward GEMMs, merged, 256x128 tiles, XCD-swizzled
  k_gemm_fwd<<<dim3(1024), dim3(512), 0, stream>>>(SN, PN, Wt, Wrt, SO, RO, SOT, ROT);
  // 3) fused double layernorm -> final
  k_ln<<<dim3(8192), dim3(256), 0, stream>>>(SO, RO, ga, ba, gr, br, out);
  // 4) Hebbian update GEMMs, 128x256 tiles, in-LDS A-transpose, split-K=32
  k_gemm_upd<<<dim3(512), dim3(512), 0, stream>>>(SN, SOT, PN, ROT, part);
  // 5) reduce partials + scale + row L2-normalize
  k_finalize<<<dim3(512, 2), dim3(256), 0, stream>>>(W, Wr, part, alpha, decay, out + 16777216);
}